// Round 4
// baseline (624.109 us; speedup 1.0000x reference)
//
#include <hip/hip_runtime.h>
#include <hip/hip_bf16.h>
#include <cstdint>

// Problem constants
#define D_DIM  2048
#define T_DIM  4096
#define B_DIM  2
#define M_DIM  8192   // B*T
#define DG_DIM 2048
#define N2_DIM 8192   // D*W (W=4)
#define K_DIM  2048

typedef __bf16 bf16x8 __attribute__((ext_vector_type(8)));
typedef __bf16 bf16x4 __attribute__((ext_vector_type(4)));
typedef float  f32x16 __attribute__((ext_vector_type(16)));

__device__ __forceinline__ void gload_lds16(const void* g, void* l) {
  __builtin_amdgcn_global_load_lds(
      (__attribute__((address_space(1))) void*)g,
      (__attribute__((address_space(3))) void*)l, 16, 0, 0);
}

__device__ __forceinline__ float silu_f(float a) {
  return a / (1.f + __expf(-a));
}

// ---------------------------------------------------------------------------
// Merged cast kernel: x->bf16, w1->bf16, w2->bf16 with ROW PERMUTATION.
// w2 permutation (for 32x32 MFMA epilogue): dest row C decomposes as
//   C = 128*Bk + 64*wn + 32*jn + 16*cl4 + dl
//   d = 32*Bk + 16*wn + dl,  j = cl4 + 2*jn,  orig row k = 4*d + j.
// Then in the MFMA C-layout, lane (cl=16*cl4+dl) block jn holds tap cl4+2*jn
// of d -> one shfl_xor(16) completes the 4-tap sum.
// ---------------------------------------------------------------------------
#define NX4  (M_DIM * D_DIM / 4)
#define NW14 (DG_DIM * D_DIM / 4)
#define NW24 (N2_DIM * DG_DIM / 4)

__global__ void cast_all(const float* __restrict__ x, const float* __restrict__ w1,
                         const float* __restrict__ w2, __bf16* __restrict__ xb,
                         __bf16* __restrict__ w1b, __bf16* __restrict__ w2b) {
  int i = blockIdx.x * blockDim.x + threadIdx.x;
  const float4* src;
  bf16x4* dst;
  if (i < NX4) {
    src = (const float4*)x + i;
    dst = (bf16x4*)xb + i;
  } else if (i < NX4 + NW14) {
    int i2 = i - NX4;
    src = (const float4*)w1 + i2;
    dst = (bf16x4*)w1b + i2;
  } else {
    int i3 = i - (NX4 + NW14);
    if (i3 >= NW24) return;
    const int row = i3 >> 9;           // dest row C (512 float4 per K=2048 row)
    const int pos = i3 & 511;
    const int Bk = row >> 7;
    const int wn = (row >> 6) & 1, jn = (row >> 5) & 1;
    const int cl4 = (row >> 4) & 1, dl = row & 15;
    const int d = 32 * Bk + 16 * wn + dl;
    const int k = 4 * d + cl4 + 2 * jn;
    src = (const float4*)w2 + (size_t)k * 512 + pos;
    dst = (bf16x4*)w2b + i3;
  }
  float4 v = *src;
  bf16x4 o;
  o[0] = (__bf16)v.x; o[1] = (__bf16)v.y; o[2] = (__bf16)v.z; o[3] = (__bf16)v.w;
  *dst = o;
}

// ---------------------------------------------------------------------------
// Shared K-loop: 128x128 tile, BK=64, XOR-swizzled LDS, mfma_f32_32x32x16.
// LDS row r (8 chunks of 16B): global chunk c stored at slot (c ^ (r&7)).
// Wave tile 64x64 = 2x2 blocks of 32x32. A/B frag: row/col = lane&31,
// k = (lane>>5)*8 + e  -> chunk = ks*2 + (lane>>5).
// ---------------------------------------------------------------------------

// GEMM1: H[m][n] = silu( sum_k A[m][k] * B[n][k] )   A=x_bf16, B=w1_bf16
__global__ __launch_bounds__(256) void gemm1_silu(
    const __bf16* __restrict__ A, const __bf16* __restrict__ B,
    __bf16* __restrict__ H) {
  constexpr int K = K_DIM, N = DG_DIM;
  __shared__ __bf16 sA[128 * 64];
  __shared__ __bf16 sB[128 * 64];
  const int tid  = threadIdx.x;
  const int lane = tid & 63;
  const int wv   = tid >> 6;
  const int wm   = wv >> 1, wn = wv & 1;
  const int cl31 = lane & 31, kh = lane >> 5;
  const int m0 = blockIdx.y * 128, n0 = blockIdx.x * 128;

  f32x16 acc[2][2] = {};

  const int g  = lane >> 3;
  const int cl = lane & 7;
  const int cg = cl ^ g;                 // global chunk this lane fetches
  const __bf16* gA[4];
  const __bf16* gB[4];
  int loff[4];
#pragma unroll
  for (int inst = 0; inst < 4; inst++) {
    const int r = (inst * 4 + wv) * 8 + g;
    gA[inst]   = A + (size_t)(m0 + r) * K + cg * 8;
    gB[inst]   = B + (size_t)(n0 + r) * K + cg * 8;
    loff[inst] = ((inst * 4 + wv) * 64 + lane) * 8;
  }

  for (int k0 = 0; k0 < K; k0 += 64) {
#pragma unroll
    for (int inst = 0; inst < 4; inst++)
      gload_lds16(gA[inst] + k0, sA + loff[inst]);
#pragma unroll
    for (int inst = 0; inst < 4; inst++)
      gload_lds16(gB[inst] + k0, sB + loff[inst]);
    __syncthreads();
#pragma unroll
    for (int ks = 0; ks < 4; ks++) {
      const int chunk = ks * 2 + kh;
      bf16x8 af[2], bq[2];
#pragma unroll
      for (int im = 0; im < 2; im++) {
        const int row = wm * 64 + im * 32 + cl31;
        af[im] = *(const bf16x8*)(sA + row * 64 + ((chunk ^ (row & 7)) * 8));
      }
#pragma unroll
      for (int jn = 0; jn < 2; jn++) {
        const int row = wn * 64 + jn * 32 + cl31;
        bq[jn] = *(const bf16x8*)(sB + row * 64 + ((chunk ^ (row & 7)) * 8));
      }
#pragma unroll
      for (int im = 0; im < 2; im++)
#pragma unroll
        for (int jn = 0; jn < 2; jn++)
          acc[im][jn] = __builtin_amdgcn_mfma_f32_32x32x16_bf16(
              af[im], bq[jn], acc[im][jn], 0, 0, 0);
    }
    __syncthreads();
  }

  // epilogue. C layout: col=lane&31, row=(reg&3)+8*(reg>>2)+4*(lane>>5)
#pragma unroll
  for (int im = 0; im < 2; im++) {
#pragma unroll
    for (int jn = 0; jn < 2; jn++) {
      const int col = n0 + wn * 64 + jn * 32 + cl31;
#pragma unroll
      for (int reg = 0; reg < 16; reg++) {
        const int row = m0 + wm * 64 + im * 32 + 4 * kh + (reg & 3) + 8 * (reg >> 2);
        H[(size_t)row * N + col] = (__bf16)silu_f(acc[im][jn][reg]);
      }
    }
  }
}

// GEMM2 + fused conv. B = permuted w2 (see cast_all). Lane (cl4,dl) block jn
// holds flat[:, 4*d + cl4 + 2*jn] for d = (n0>>2)+16*wn+dl.
// y[m][d] = sum_j (flat_j + b2[4d+j]) * x[b, t+j-3, d];  out = silu(y)
__global__ __launch_bounds__(256) void gemm2_conv_silu(
    const __bf16* __restrict__ A, const __bf16* __restrict__ B,
    const float* __restrict__ b2, const float* __restrict__ x,
    float* __restrict__ out) {
  constexpr int K = K_DIM;
  __shared__ __bf16 sA[128 * 64];
  __shared__ __bf16 sB[128 * 64];
  const int tid  = threadIdx.x;
  const int lane = tid & 63;
  const int wv   = tid >> 6;
  const int wm   = wv >> 1, wn = wv & 1;
  const int cl31 = lane & 31, kh = lane >> 5;
  const int m0 = blockIdx.y * 128, n0 = blockIdx.x * 128;

  f32x16 acc[2][2] = {};

  const int g  = lane >> 3;
  const int cl = lane & 7;
  const int cg = cl ^ g;
  const __bf16* gA[4];
  const __bf16* gB[4];
  int loff[4];
#pragma unroll
  for (int inst = 0; inst < 4; inst++) {
    const int r = (inst * 4 + wv) * 8 + g;
    gA[inst]   = A + (size_t)(m0 + r) * K + cg * 8;
    gB[inst]   = B + (size_t)(n0 + r) * K + cg * 8;
    loff[inst] = ((inst * 4 + wv) * 64 + lane) * 8;
  }

  for (int k0 = 0; k0 < K; k0 += 64) {
#pragma unroll
    for (int inst = 0; inst < 4; inst++)
      gload_lds16(gA[inst] + k0, sA + loff[inst]);
#pragma unroll
    for (int inst = 0; inst < 4; inst++)
      gload_lds16(gB[inst] + k0, sB + loff[inst]);
    __syncthreads();
#pragma unroll
    for (int ks = 0; ks < 4; ks++) {
      const int chunk = ks * 2 + kh;
      bf16x8 af[2], bq[2];
#pragma unroll
      for (int im = 0; im < 2; im++) {
        const int row = wm * 64 + im * 32 + cl31;
        af[im] = *(const bf16x8*)(sA + row * 64 + ((chunk ^ (row & 7)) * 8));
      }
#pragma unroll
      for (int jn = 0; jn < 2; jn++) {
        const int row = wn * 64 + jn * 32 + cl31;
        bq[jn] = *(const bf16x8*)(sB + row * 64 + ((chunk ^ (row & 7)) * 8));
      }
#pragma unroll
      for (int im = 0; im < 2; im++)
#pragma unroll
        for (int jn = 0; jn < 2; jn++)
          acc[im][jn] = __builtin_amdgcn_mfma_f32_32x32x16_bf16(
              af[im], bq[jn], acc[im][jn], 0, 0, 0);
    }
    __syncthreads();
  }

  // Fused conv epilogue. Lane owns d = (n0>>2)+16*wn+dl, taps {cl4, cl4+2}.
  const int dl  = lane & 15;
  const int cl4 = (lane >> 4) & 1;
  const int d   = (n0 >> 2) + wn * 16 + dl;
  const float b_lo = b2[4 * d + cl4];
  const float b_hi = b2[4 * d + cl4 + 2];

#pragma unroll
  for (int im = 0; im < 2; im++) {
    const int m_blk = m0 + wm * 64 + im * 32 + 4 * kh;   // + (reg&3)+8*(reg>>2)
    const int b  = m_blk >> 12;                           // T=4096
    const int tb = m_blk & 4095;
    const float* xb_ = x + ((size_t)b << 12) * D_DIM + d;
    float* ob_ = out + ((size_t)m_blk) * D_DIM + d;
#pragma unroll
    for (int reg = 0; reg < 16; reg++) {
      const int ro = (reg & 3) + 8 * (reg >> 2);
      const int tr = tb + ro;
      const int t0 = tr + cl4 - 3;   // tap cl4
      const int t1 = tr + cl4 - 1;   // tap cl4+2
      const float xv0 = (t0 >= 0) ? xb_[(size_t)t0 * D_DIM] : 0.f;
      const float xv1 = (t1 >= 0) ? xb_[(size_t)t1 * D_DIM] : 0.f;
      float p = (acc[im][0][reg] + b_lo) * xv0 + (acc[im][1][reg] + b_hi) * xv1;
      p += __shfl_xor(p, 16);
      if (cl4 == 0) ob_[(size_t)ro * D_DIM] = silu_f(p);
    }
  }
}

extern "C" void kernel_launch(void* const* d_in, const int* in_sizes, int n_in,
                              void* d_out, int out_size, void* d_ws, size_t ws_size,
                              hipStream_t stream) {
  (void)in_sizes; (void)n_in; (void)out_size; (void)ws_size;
  const float* x  = (const float*)d_in[0];
  const float* w1 = (const float*)d_in[1];
  const float* w2 = (const float*)d_in[2];
  const float* b2 = (const float*)d_in[3];
  float* out = (float*)d_out;

  __bf16* xb  = (__bf16*)d_ws;                        // 8192*2048
  __bf16* w1b = xb  + (size_t)M_DIM * D_DIM;          // 2048*2048
  __bf16* w2b = w1b + (size_t)DG_DIM * D_DIM;         // 8192*2048 (permuted)
  __bf16* hb  = w2b + (size_t)N2_DIM * DG_DIM;        // 8192*2048

  {
    int total = NX4 + NW14 + NW24;
    cast_all<<<(total + 255) / 256, 256, 0, stream>>>(x, w1, w2, xb, w1b, w2b);
  }

  gemm1_silu<<<dim3(DG_DIM / 128, M_DIM / 128), 256, 0, stream>>>(xb, w1b, hb);
  gemm2_conv_silu<<<dim3(N2_DIM / 128, M_DIM / 128), 256, 0, stream>>>(
      hb, w2b, b2, x, out);
}